// Round 1
// baseline (2270.930 us; speedup 1.0000x reference)
//
#include <hip/hip_runtime.h>
#include <stdint.h>

// ---------------------------------------------------------------------------
// NeuralFingerprint on MI355X (gfx950). Inputs float32 (runtime-probed),
// canonicalized to bf16. R7: k_gemm is latency/prologue-bound (short K: 2-8
// chunks/block, 10% MfmaUtil, 25% HBM). Changes:
//   (1) persistent tile loop: each block walks TPB bm-tiles (same bn), the
//       double-buffered chunk pipeline runs across tile boundaries, so the
//       ~900-cyc HBM prologue is paid once per block, not once per tile, and
//       epilogue stores overlap the next tile's in-flight staging loads.
//   (2) co-XCD swizzle: the nbn blocks sharing an A tile-row get linear IDs
//       congruent mod 8 (same XCD L2) and temporally adjacent -> A fetched
//       once from HBM (R6's consecutive-ID layout put sharers on different
//       XCDs; FETCH showed A fetched 2x).
// ---------------------------------------------------------------------------

typedef __attribute__((ext_vector_type(8))) short short8;
typedef __attribute__((ext_vector_type(4))) float f32x4;

#define NATOMS 131072
#define NDEG   32768
#define NMOL   4096

__device__ __forceinline__ float b2f(unsigned short u) {
  return __uint_as_float(((unsigned)u) << 16);
}
__device__ __forceinline__ unsigned short f2b(float f) {
  unsigned u = __float_as_uint(f);
  return (unsigned short)((u + 0x7fffu + ((u >> 16) & 1u)) >> 16);
}
__device__ __forceinline__ void async16(const void* g, void* l) {
  __builtin_amdgcn_global_load_lds(
      (const __attribute__((address_space(1))) void*)g,
      (__attribute__((address_space(3))) void*)l, 16, 0, 0);
}

// ---------------------------------------------------------------------------
// dtype probe: f32 buffers read-as-bf16 show garbage-exponent odd ushorts.
// ---------------------------------------------------------------------------
__global__ void k_flag(const unsigned short* __restrict__ a, int* __restrict__ flag) {
  int t = threadIdx.x;
  float x = b2f(a[t]), y = b2f(a[t + 256]);
  int bad = (fabsf(x) > 1e6f) || (fabsf(y) > 1e6f) || (x != x) || (y != y);
  if (bad) atomicOr(flag, 1);
}

// convert n2 bf16-pairs: src f32 (flag=1) or bf16 (flag=0)
__global__ void k_cvt(const void* __restrict__ src, unsigned short* __restrict__ dst,
                      int n2, const int* __restrict__ flag) {
  int i = blockIdx.x * 256 + threadIdx.x;
  if (i >= n2) return;
  if (*flag) {
    const float* s = (const float*)src;
    ((unsigned*)dst)[i] = (unsigned)f2b(s[2 * i]) | ((unsigned)f2b(s[2 * i + 1]) << 16);
  } else {
    ((unsigned*)dst)[i] = ((const unsigned*)src)[i];
  }
}

// ---------------------------------------------------------------------------
// one-shot prep: 13 weight transposes + 5 bias copies, f32/bf16 dual dtype.
// ---------------------------------------------------------------------------
struct PrepDesc { const void* src; unsigned short* dst; int K; int N; };
struct PrepArgs { PrepDesc d[18]; };

__global__ void k_prep(PrepArgs a, const int* __restrict__ flag) {
  const PrepDesc de = a.d[blockIdx.y];
  int elems = de.K ? de.K * de.N : de.N;
  int idx = blockIdx.x * 256 + threadIdx.x;
  if (idx >= elems) return;
  unsigned short v = (*flag) ? f2b(((const float*)de.src)[idx])
                             : ((const unsigned short*)de.src)[idx];
  if (de.K) {
    int k = idx / de.N, n = idx - k * de.N;
    de.dst[(size_t)n * de.K + k] = v;       // [K,N] -> [N,K]
  } else {
    de.dst[idx] = v;
  }
}

// ---------------------------------------------------------------------------
// GEMM: out[orow,N] = A[M,K] * Wt[N,K]^T (+bias[col]) (+actS[orow,col])
// orow = idx ? idx[row*idxStride] : row. In-place safe (actS == out).
// Persistent: 1D grid of (M/128/TPB)*(N/128) blocks; each block processes
// TPB consecutive bm-tiles at fixed bn. Block-ID remap puts the nbn blocks
// sharing an A tile-row on the same XCD (lin ≡ same mod 8), adjacent in time.
// Double-buffered LDS chunk pipeline is continuous across tile boundaries.
// ---------------------------------------------------------------------------
__global__ __launch_bounds__(256) void k_gemm(
    const unsigned short* __restrict__ A, const unsigned short* __restrict__ Wt,
    int M, int N, int K, int TPB,
    const unsigned short* __restrict__ bias,
    const unsigned short* __restrict__ actS,
    const int* __restrict__ idx, int idxStride,
    unsigned short* __restrict__ out)
{
  __shared__ __attribute__((aligned(16))) unsigned short ls0A[128 * 64];
  __shared__ __attribute__((aligned(16))) unsigned short ls0B[128 * 64];
  __shared__ __attribute__((aligned(16))) unsigned short ls1A[128 * 64];
  __shared__ __attribute__((aligned(16))) unsigned short ls1B[128 * 64];

  const int tid  = threadIdx.x;
  const int wave = tid >> 6;
  const int lane = tid & 63;

  // --- block remap: lin -> (bm_grp, bnb); A-sharers co-XCD ---
  const int nbn  = N >> 7;
  const int nbmg = gridDim.x / nbn;
  int bm_grp, bnb;
  {
    int lin = blockIdx.x;
    if ((nbmg & 7) == 0) {            // bijective XCD grouping
      int r = lin & 7, rest = lin >> 3;
      bnb = rest % nbn;
      bm_grp = (rest / nbn) * 8 + r;
    } else {                          // fallback: plain row-major
      bnb = lin % nbn;
      bm_grp = lin / nbn;
    }
  }
  const int bn = bnb * 128;
  const int bmBaseRow = bm_grp * TPB * 128;   // first row of first tile

  // staging: waves 0,1 -> A, waves 2,3 -> B. chunk c holds global
  // (m=c>>3, kc=(c&7)^(m&7)) -> XOR swizzle for conflict-light b128 reads.
  const unsigned short* gsrc[8];
  int ldoff[8];
  unsigned short* sb0;
  unsigned short* sb1;
  {
    const unsigned short* gb = (wave < 2) ? (A + (size_t)bmBaseRow * K)
                                          : (Wt + (size_t)bn * K);
    sb0 = (wave < 2) ? ls0A : ls0B;
    sb1 = (wave < 2) ? ls1A : ls1B;
    int ib = (wave & 1) * 8;
#pragma unroll
    for (int t = 0; t < 8; t++) {
      int c = (ib + t) * 64 + lane;
      int m = c >> 3;
      int kc = (c & 7) ^ (m & 7);
      gsrc[t] = gb + (size_t)m * K + kc * 8;
      ldoff[t] = (ib + t) * 512;
    }
  }
  // per-tile pointer rollover: A jumps +128 rows (net), B rewinds to chunk 0
  const int rollAdd = (wave < 2) ? (127 * K) : (-K);

  const int wm = (wave & 1) * 64;
  const int wn = (wave >> 1) * 64;
  const int r15 = lane & 15;
  const int quad = lane >> 4;
  const int x7 = lane & 7;
  const int nk = K >> 6;
  const int G = TPB * nk;             // total chunks this block stages

  // scatter-row prefetch for tile 0 (overlaps its whole K-loop)
  int orow[4][4];
#pragma unroll
  for (int i = 0; i < 4; i++)
#pragma unroll
    for (int r = 0; r < 4; r++) {
      int row = bmBaseRow + wm + i * 16 + quad * 4 + r;
      orow[i][r] = idx ? idx[row * idxStride] : row;
    }

  f32x4 acc[4][4];
  f32x4 zero = {0.f, 0.f, 0.f, 0.f};
#pragma unroll
  for (int i = 0; i < 4; i++)
#pragma unroll
    for (int j = 0; j < 4; j++) acc[i][j] = zero;

  int sc = 0;   // chunk-within-tile of the NEXT stage target
  // prologue: stage global chunk 0 into buffer 0
  {
#pragma unroll
    for (int t = 0; t < 8; t++) { async16(gsrc[t], sb0 + ldoff[t]); gsrc[t] += 64; }
    if (++sc == nk) { sc = 0;
#pragma unroll
      for (int t = 0; t < 8; t++) gsrc[t] += rollAdd;
    }
  }

  int cc = 0;     // chunk index within current tile
  int tile = 0;   // current tile within this block
  for (int g = 0; g < G; g++) {
    __syncthreads();                       // publish chunk g (drains prefetch)
    if (g + 1 < G) {                       // prefetch chunk g+1 into other buf
      unsigned short* d = ((g + 1) & 1) ? sb1 : sb0;
#pragma unroll
      for (int t = 0; t < 8; t++) { async16(gsrc[t], d + ldoff[t]); gsrc[t] += 64; }
      if (++sc == nk) { sc = 0;
#pragma unroll
        for (int t = 0; t < 8; t++) gsrc[t] += rollAdd;
      }
    }
    const unsigned short* cA = (g & 1) ? ls1A : ls0A;
    const unsigned short* cB = (g & 1) ? ls1B : ls0B;
#pragma unroll
    for (int ks = 0; ks < 2; ks++) {
      short8 af[4], bf[4];
      int kc = ks * 4 + quad;
      int xo = (kc ^ x7) * 8;
#pragma unroll
      for (int f = 0; f < 4; f++) {
        af[f] = *(const short8*)&cA[(wm + f * 16 + r15) * 64 + xo];
        bf[f] = *(const short8*)&cB[(wn + f * 16 + r15) * 64 + xo];
      }
#pragma unroll
      for (int i = 0; i < 4; i++)
#pragma unroll
        for (int j = 0; j < 4; j++)
          acc[i][j] = __builtin_amdgcn_mfma_f32_16x16x32_bf16(af[i], bf[j], acc[i][j], 0, 0, 0);
    }

    if (++cc == nk) {                      // tile finished -> epilogue
      cc = 0;
      // D layout: row = quad*4+reg, col = lane&15 (m89/m91 verified).
      // Runs after next chunk's loads were issued: stores overlap staging.
#pragma unroll
      for (int i = 0; i < 4; i++) {
#pragma unroll
        for (int r = 0; r < 4; r++) {
          size_t rb = (size_t)orow[i][r] * N;
#pragma unroll
          for (int j = 0; j < 4; j++) {
            int col = bn + wn + j * 16 + r15;
            float v = acc[i][j][r];
            if (bias) v += b2f(bias[col]);
            if (actS) v += b2f(actS[rb + col]);
            out[rb + col] = f2b(v);
          }
        }
      }
      tile++;
      if (tile < TPB) {
        // reset accumulators + prefetch next tile's scatter rows
#pragma unroll
        for (int i = 0; i < 4; i++)
#pragma unroll
          for (int j = 0; j < 4; j++) acc[i][j] = zero;
        int rowBase = bmBaseRow + tile * 128;
#pragma unroll
        for (int i = 0; i < 4; i++)
#pragma unroll
          for (int r = 0; r < 4; r++) {
            int row = rowBase + wm + i * 16 + quad * 4 + r;
            orow[i][r] = idx ? idx[row * idxStride] : row;
          }
      }
    }
  }
}

// ---------------------------------------------------------------------------
// softmax + molecule segment-sum over a logits chunk L[65536, 512] (bf16).
// Chunk holds atoms [chunkBase, chunkBase+65536) = 16 atoms per molecule
// (stride 4096). One wave per molecule-slot; lane owns 8 contiguous cols.
// ---------------------------------------------------------------------------
__global__ __launch_bounds__(256) void k_smseg(
    const unsigned short* __restrict__ L, const int* __restrict__ mol,
    int chunkBase, int accum, float* __restrict__ fp)
{
  int slot = blockIdx.x * 4 + (threadIdx.x >> 6);   // 0..4095
  int lane = threadIdx.x & 63;
  float acc[8];
#pragma unroll
  for (int c = 0; c < 8; c++) acc[c] = 0.f;

  for (int k = 0; k < 16; k++) {
    int rloc = slot + (k << 12);
    short8 v = *(const short8*)&L[(size_t)rloc * 512 + lane * 8];
    float f[8];
    float m = -1e30f;
#pragma unroll
    for (int c = 0; c < 8; c++) { f[c] = b2f((unsigned short)v[c]); m = fmaxf(m, f[c]); }
#pragma unroll
    for (int s = 1; s <= 32; s <<= 1) m = fmaxf(m, __shfl_xor(m, s, 64));
    float sum = 0.f;
#pragma unroll
    for (int c = 0; c < 8; c++) { f[c] = __expf(f[c] - m); sum += f[c]; }
#pragma unroll
    for (int s = 1; s <= 32; s <<= 1) sum += __shfl_xor(sum, s, 64);
    float inv = 1.0f / sum;
#pragma unroll
    for (int c = 0; c < 8; c++) acc[c] += f[c] * inv;
  }

  int molid = mol[chunkBase + slot];
  float* dst = fp + (size_t)molid * 512 + lane * 8;
  if (accum) {
#pragma unroll
    for (int c = 0; c < 8; c++) dst[c] += acc[c];
  } else {
#pragma unroll
    for (int c = 0; c < 8; c++) dst[c] = acc[c];
  }
}

// ---------------------------------------------------------------------------
// gather: G[r] = [ sum_{j<=d} feat[anbr[r][j]], sum_{j<d} bond[bnbr[r][j]] ]
// feat canonical bf16; bond raw input (dual dtype via flag).
// ---------------------------------------------------------------------------
__global__ __launch_bounds__(256) void k_gather(
    const unsigned short* __restrict__ feat, const void* __restrict__ bond,
    const int* __restrict__ anbr, const int* __restrict__ bnbr,
    int d, int fin, unsigned short* __restrict__ G, const int* __restrict__ flag)
{
  int row = blockIdx.x * 4 + (threadIdx.x >> 6);
  int lane = threadIdx.x & 63;
  int W = fin + 64;
  int fl = *flag;
  const int* ar = anbr + (size_t)row * (d + 1);
  const int* br = bnbr + (size_t)row * d;
  for (int e2 = lane; e2 * 2 < W; e2 += 64) {
    int e = e2 * 2;
    float a0 = 0.f, a1 = 0.f;
    if (e < fin) {
      for (int j = 0; j <= d; j++) {
        unsigned p = *(const unsigned*)((const unsigned short*)feat + (size_t)ar[j] * fin + e);
        a0 += b2f((unsigned short)p);
        a1 += b2f((unsigned short)(p >> 16));
      }
    } else {
      int eb = e - fin;
      if (fl) {
        const float* bp = (const float*)bond;
        for (int j = 0; j < d; j++) {
          size_t o = (size_t)br[j] * 64 + eb;
          a0 += bp[o]; a1 += bp[o + 1];
        }
      } else {
        const unsigned short* bp = (const unsigned short*)bond;
        for (int j = 0; j < d; j++) {
          unsigned p = *(const unsigned*)(bp + (size_t)br[j] * 64 + eb);
          a0 += b2f((unsigned short)p);
          a1 += b2f((unsigned short)(p >> 16));
        }
      }
    }
    *(unsigned*)(G + (size_t)row * W + e) = (unsigned)f2b(a0) | ((unsigned)f2b(a1) << 16);
  }
}

// ---------------------------------------------------------------------------
// BatchNorm stats + normalize/ReLU in place (canonical bf16)
// ---------------------------------------------------------------------------
__global__ __launch_bounds__(256) void k_bnstats(const unsigned short* __restrict__ act,
                                                 float* __restrict__ st, int C) {
  int t = threadIdx.x;
  size_t r0 = (size_t)blockIdx.x * 256;
  int two = (C == 512);
  float s0 = 0, q0 = 0, s1 = 0, q1 = 0;
  for (int r = 0; r < 256; r++) {
    const unsigned short* rp = act + (r0 + r) * (size_t)C;
    float v = b2f(rp[t]); s0 += v; q0 += v * v;
    if (two) { float w = b2f(rp[t + 256]); s1 += w; q1 += w * w; }
  }
  atomicAdd(&st[t], s0);
  atomicAdd(&st[C + t], q0);
  if (two) { atomicAdd(&st[t + 256], s1); atomicAdd(&st[C + t + 256], q1); }
}
__global__ __launch_bounds__(256) void k_bnrelu(unsigned short* __restrict__ act,
                                                const float* __restrict__ st, int C, float invN) {
  size_t i = (size_t)blockIdx.x * 256 + threadIdx.x;
  unsigned p = ((unsigned*)act)[i];
  int c0 = (int)((2 * i) & (size_t)(C - 1));
  float mu0 = st[c0] * invN, mu1 = st[c0 + 1] * invN;
  float sc0 = rsqrtf(st[C + c0] * invN - mu0 * mu0 + 1e-5f);
  float sc1 = rsqrtf(st[C + c0 + 1] * invN - mu1 * mu1 + 1e-5f);
  float v0 = fmaxf((b2f((unsigned short)p) - mu0) * sc0, 0.f);
  float v1 = fmaxf((b2f((unsigned short)(p >> 16)) - mu1) * sc1, 0.f);
  ((unsigned*)act)[i] = (unsigned)f2b(v0) | ((unsigned)f2b(v1) << 16);
}

__global__ void k_out(const float* __restrict__ fp, void* __restrict__ out,
                      const int* __restrict__ flag) {
  size_t i = (size_t)blockIdx.x * 256 + threadIdx.x;   // pair index
  float a = fp[2 * i], b = fp[2 * i + 1];
  if (*flag) {
    ((float*)out)[2 * i] = a;
    ((float*)out)[2 * i + 1] = b;
  } else {
    ((unsigned*)out)[i] = (unsigned)f2b(a) | ((unsigned)f2b(b) << 16);
  }
}

// ---------------------------------------------------------------------------
extern "C" void kernel_launch(void* const* d_in, const int* in_sizes, int n_in,
                              void* d_out, int out_size, void* d_ws, size_t ws_size,
                              hipStream_t stream)
{
  const void* atomRaw = d_in[0];
  const void* bondRaw = d_in[1];
  const int* mol = (const int*)d_in[2];

  const int* anbr[4]; const int* bnbr[4];
  if (in_sizes[4] == NDEG) {       // dict order: anbr_d1, bnbr_d1, anbr_d2, ...
    for (int g = 0; g < 4; g++) { anbr[g] = (const int*)d_in[3 + 2 * g]; bnbr[g] = (const int*)d_in[4 + 2 * g]; }
  } else {                         // signature order
    for (int g = 0; g < 4; g++) { anbr[g] = (const int*)d_in[3 + g]; bnbr[g] = (const int*)d_in[7 + g]; }
  }
  const void* W_self[2] = {d_in[11], d_in[17]};
  const void* biasL[2]  = {d_in[12], d_in[18]};
  const void* W_deg[2][4];
  for (int g = 0; g < 4; g++) { W_deg[0][g] = d_in[13 + g]; W_deg[1][g] = d_in[19 + g]; }
  const void* W_out[3] = {d_in[23], d_in[25], d_in[27]};
  const void* b_out[3] = {d_in[24], d_in[26], d_in[28]};

  // ---- workspace carve (~224 MiB; atomC aliases Y) ----
  char* p = (char*)d_ws;
  auto alloc = [&](size_t bytes) { void* r = p; p += (bytes + 255) & ~(size_t)255; return r; };
  unsigned short* X  = (unsigned short*)alloc((size_t)NATOMS * 256 * 2);   // 64 MiB
  unsigned short* G  = (unsigned short*)alloc((size_t)NDEG * 320 * 2);     // 20 MiB
  float* fp          = (float*)alloc((size_t)NMOL * 512 * 4);              // 8 MiB
  unsigned short* wtSelf0 = (unsigned short*)alloc(128 * 256 * 2);
  unsigned short* wtSelf1 = (unsigned short*)alloc(256 * 512 * 2);
  unsigned short* wtDeg0[4], *wtDeg1[4];
  for (int g = 0; g < 4; g++) wtDeg0[g] = (unsigned short*)alloc(192 * 256 * 2);
  for (int g = 0; g < 4; g++) wtDeg1[g] = (unsigned short*)alloc(320 * 512 * 2);
  unsigned short* wtOut0 = (unsigned short*)alloc(128 * 512 * 2);
  unsigned short* wtOut1 = (unsigned short*)alloc(256 * 512 * 2);
  unsigned short* wtOut2 = (unsigned short*)alloc(512 * 512 * 2);
  unsigned short* biasC0 = (unsigned short*)alloc(256 * 2);
  unsigned short* biasC1 = (unsigned short*)alloc(512 * 2);
  unsigned short* bOutC[3];
  for (int g = 0; g < 3; g++) bOutC[g] = (unsigned short*)alloc(512 * 2);
  float* st = (float*)alloc(2 * 512 * 4);
  int* flag = (int*)alloc(256);
  unsigned short* Y = (unsigned short*)alloc((size_t)NATOMS * 512 * 2);    // 128 MiB
  unsigned short* atomC = Y;   // alias: atomC (32 MiB) dead before first Y write

  size_t need = (size_t)(p - (char*)d_ws);
  if (ws_size < need) {                        // clean fail instead of OOB fault
    hipMemsetAsync(d_out, 0, (size_t)out_size * 2, stream);
    return;
  }

  const float invN = 1.0f / (float)NATOMS;
  const int MH = NATOMS / 2;                   // 65536-atom logits chunks

  hipMemsetAsync(flag, 0, 4, stream);
  k_flag<<<dim3(1), dim3(256), 0, stream>>>((const unsigned short*)atomRaw, flag);

  // canonical bf16 atom copy (into Y-alias)
  k_cvt<<<dim3(NATOMS * 64 / 256), dim3(256), 0, stream>>>(atomRaw, atomC, NATOMS * 64, flag);

  // one launch: 13 transposes + 5 bias copies
  {
    PrepArgs pa;
    int n = 0;
    auto T = [&](const void* s, unsigned short* d, int K, int N) { pa.d[n++] = {s, d, K, N}; };
    auto C = [&](const void* s, unsigned short* d, int N)        { pa.d[n++] = {s, d, 0, N}; };
    T(W_self[0], wtSelf0, 128, 256);
    T(W_self[1], wtSelf1, 256, 512);
    for (int g = 0; g < 4; g++) T(W_deg[0][g], wtDeg0[g], 192, 256);
    for (int g = 0; g < 4; g++) T(W_deg[1][g], wtDeg1[g], 320, 512);
    T(W_out[0], wtOut0, 128, 512);
    T(W_out[1], wtOut1, 256, 512);
    T(W_out[2], wtOut2, 512, 512);
    C(biasL[0], biasC0, 256);
    C(biasL[1], biasC1, 512);
    for (int g = 0; g < 3; g++) C(b_out[g], bOutC[g], 512);
    k_prep<<<dim3(1024, 18), dim3(256), 0, stream>>>(pa, flag);
  }

  // persistent GEMM launcher: pick largest power-of-two TPB keeping >=512
  // blocks (2/CU) for drain-hiding overlap; nbmg stays %8==0 for the swizzle.
  auto GEMM = [&](const unsigned short* A, const unsigned short* Wt, int M, int N, int K,
                  const unsigned short* bias, const unsigned short* actS,
                  const int* idx, int idxStride, unsigned short* out) {
    int nbn = N / 128, nT = M / 128;
    int tpb = 1;
    while (tpb < 8 && (nT % (tpb * 2)) == 0 && (nT / (tpb * 2)) * nbn >= 512) tpb *= 2;
    int nblocks = (nT / tpb) * nbn;
    k_gemm<<<dim3(nblocks), dim3(256), 0, stream>>>(A, Wt, M, N, K, tpb, bias, actS,
                                                    idx, idxStride, out);
  };

  // fingerprint round: logits via k_gemm into scratch (bf16, M=65536 chunks),
  // then k_smseg. round r uses scratch buffer dead at that point.
  auto FPROUND = [&](const unsigned short* A, const unsigned short* WtO, int K,
                     const unsigned short* bias, unsigned short* scratch, int firstRound) {
    for (int c = 0; c < 2; c++) {
      GEMM(A + (size_t)c * MH * K, WtO, MH, 512, K, bias, nullptr, nullptr, 0, scratch);
      k_smseg<<<dim3(NMOL / 4), dim3(256), 0, stream>>>(scratch, mol, c * MH,
                                                        (firstRound && c == 0) ? 0 : 1, fp);
    }
  };

  // ---- fp round 0 (atomC in Y-alias, K=128; scratch = X, not yet live) ----
  FPROUND(atomC, wtOut0, 128, bOutC[0], X, 1);

  // ---- conv layer 0 (128 -> 256), in-place nbr add on X ----
  GEMM(atomC, wtSelf0, NATOMS, 256, 128, biasC0, nullptr, nullptr, 0, X);
  for (int g = 0; g < 4; g++) {
    int d = g + 1;
    k_gather<<<dim3(NDEG / 4), dim3(256), 0, stream>>>(atomC, bondRaw, anbr[g], bnbr[g], d, 128, G, flag);
    GEMM(G, wtDeg0[g], NDEG, 256, 192, nullptr, X, anbr[g], d + 1, X);
  }
  hipMemsetAsync(st, 0, 2 * 512 * 4, stream);
  k_bnstats<<<dim3(NATOMS / 256), dim3(256), 0, stream>>>(X, st, 256);
  k_bnrelu<<<dim3(NATOMS * 256 / 2 / 256), dim3(256), 0, stream>>>(X, st, 256, invN);

  // ---- fp round 1 (X, K=256; scratch = Y, atomC dead, Y not yet live) ----
  FPROUND(X, wtOut1, 256, bOutC[1], Y, 0);

  // ---- conv layer 1 (256 -> 512), in-place nbr add on Y ----
  GEMM(X, wtSelf1, NATOMS, 512, 256, biasC1, nullptr, nullptr, 0, Y);
  for (int g = 0; g < 4; g++) {
    int d = g + 1;
    k_gather<<<dim3(NDEG / 4), dim3(256), 0, stream>>>(X, bondRaw, anbr[g], bnbr[g], d, 256, G, flag);
    GEMM(G, wtDeg1[g], NDEG, 512, 320, nullptr, Y, anbr[g], d + 1, Y);
  }
  hipMemsetAsync(st, 0, 2 * 512 * 4, stream);
  k_bnstats<<<dim3(NATOMS / 256), dim3(256), 0, stream>>>(Y, st, 512);
  k_bnrelu<<<dim3(NATOMS * 512 / 2 / 256), dim3(256), 0, stream>>>(Y, st, 512, invN);

  // ---- fp round 2 (Y, K=512; scratch = X, dead after conv layer 1) ----
  FPROUND(Y, wtOut2, 512, bOutC[2], X, 0);

  k_out<<<dim3(NMOL * 256 / 256), dim3(256), 0, stream>>>(fp, d_out, flag);
}

// Round 2
// 1598.815 us; speedup vs baseline: 1.4204x; 1.4204x over previous
//
#include <hip/hip_runtime.h>
#include <stdint.h>

// ---------------------------------------------------------------------------
// NeuralFingerprint on MI355X (gfx950). Inputs float32 (runtime-probed),
// canonicalized to bf16. R8: GEMM is latency-bound (bytes-in-flight), and the
// latency hiding comes from block TURNOVER (R7 post-mortem: persistence cut
// blocks to capacity and regressed 1.66x despite 4x less FETCH). Changes vs R6:
//   (1) BK 64 -> 32: LDS 64KB -> 32KB/block => 5 blocks/CU (was 2), 20 waves/CU
//       to overlap each block's barrier drain. Same sync structure (dbuf +
//       one __syncthreads per chunk, prefetch issued right after the barrier).
//   (2) co-XCD block remap kept from R7 (proven: FETCH 131.8->33.9MB): A-tile
//       sharers get linear IDs congruent mod 8 (same XCD L2), near-simultaneous
//       launch -> 3 of 4 A reads become L2 hits.
//   (3) NO persistence: turnover grid (one tile per block) restored.
// ---------------------------------------------------------------------------

typedef __attribute__((ext_vector_type(8))) short short8;
typedef __attribute__((ext_vector_type(4))) float f32x4;

#define NATOMS 131072
#define NDEG   32768
#define NMOL   4096

__device__ __forceinline__ float b2f(unsigned short u) {
  return __uint_as_float(((unsigned)u) << 16);
}
__device__ __forceinline__ unsigned short f2b(float f) {
  unsigned u = __float_as_uint(f);
  return (unsigned short)((u + 0x7fffu + ((u >> 16) & 1u)) >> 16);
}
__device__ __forceinline__ void async16(const void* g, void* l) {
  __builtin_amdgcn_global_load_lds(
      (const __attribute__((address_space(1))) void*)g,
      (__attribute__((address_space(3))) void*)l, 16, 0, 0);
}

// ---------------------------------------------------------------------------
// dtype probe: f32 buffers read-as-bf16 show garbage-exponent odd ushorts.
// ---------------------------------------------------------------------------
__global__ void k_flag(const unsigned short* __restrict__ a, int* __restrict__ flag) {
  int t = threadIdx.x;
  float x = b2f(a[t]), y = b2f(a[t + 256]);
  int bad = (fabsf(x) > 1e6f) || (fabsf(y) > 1e6f) || (x != x) || (y != y);
  if (bad) atomicOr(flag, 1);
}

// convert n2 bf16-pairs: src f32 (flag=1) or bf16 (flag=0)
__global__ void k_cvt(const void* __restrict__ src, unsigned short* __restrict__ dst,
                      int n2, const int* __restrict__ flag) {
  int i = blockIdx.x * 256 + threadIdx.x;
  if (i >= n2) return;
  if (*flag) {
    const float* s = (const float*)src;
    ((unsigned*)dst)[i] = (unsigned)f2b(s[2 * i]) | ((unsigned)f2b(s[2 * i + 1]) << 16);
  } else {
    ((unsigned*)dst)[i] = ((const unsigned*)src)[i];
  }
}

// ---------------------------------------------------------------------------
// one-shot prep: 13 weight transposes + 5 bias copies, f32/bf16 dual dtype.
// ---------------------------------------------------------------------------
struct PrepDesc { const void* src; unsigned short* dst; int K; int N; };
struct PrepArgs { PrepDesc d[18]; };

__global__ void k_prep(PrepArgs a, const int* __restrict__ flag) {
  const PrepDesc de = a.d[blockIdx.y];
  int elems = de.K ? de.K * de.N : de.N;
  int idx = blockIdx.x * 256 + threadIdx.x;
  if (idx >= elems) return;
  unsigned short v = (*flag) ? f2b(((const float*)de.src)[idx])
                             : ((const unsigned short*)de.src)[idx];
  if (de.K) {
    int k = idx / de.N, n = idx - k * de.N;
    de.dst[(size_t)n * de.K + k] = v;       // [K,N] -> [N,K]
  } else {
    de.dst[idx] = v;
  }
}

// ---------------------------------------------------------------------------
// GEMM: out[orow,N] = A[M,K] * Wt[N,K]^T (+bias[col]) (+actS[orow,col])
// orow = idx ? idx[row*idxStride] : row. In-place safe (actS == out).
// Tile 128x128, BK=32, LDS 32KB/block (5 blocks/CU). 1D grid with co-XCD
// remap: the nbn blocks sharing an A tile-row sit at IDs == same (mod 8).
// LDS layout per chunk: granule (m, g') holds global granule g = g'^((m>>1)&3)
// -> ds_read_b128 of a column-slice is bank-conflict-free (8 consecutive
// lanes cover all 8 bank groups).
// ---------------------------------------------------------------------------
__global__ __launch_bounds__(256) void k_gemm(
    const unsigned short* __restrict__ A, const unsigned short* __restrict__ Wt,
    int M, int N, int K,
    const unsigned short* __restrict__ bias,
    const unsigned short* __restrict__ actS,
    const int* __restrict__ idx, int idxStride,
    unsigned short* __restrict__ out)
{
  __shared__ __attribute__((aligned(16))) unsigned short ls0A[128 * 32];
  __shared__ __attribute__((aligned(16))) unsigned short ls0B[128 * 32];
  __shared__ __attribute__((aligned(16))) unsigned short ls1A[128 * 32];
  __shared__ __attribute__((aligned(16))) unsigned short ls1B[128 * 32];

  const int tid  = threadIdx.x;
  const int wave = tid >> 6;
  const int lane = tid & 63;

  // --- co-XCD block remap: A-tile sharers congruent mod 8 ---
  const int nbn = N >> 7;
  int bmT, bnb;
  {
    int lin = blockIdx.x;
    int nT = gridDim.x / nbn;
    if ((nT & 7) == 0) {
      int r = lin & 7, rest = lin >> 3;
      bnb = rest % nbn;
      bmT = (rest / nbn) * 8 + r;
    } else {
      bnb = lin % nbn;
      bmT = lin / nbn;
    }
  }
  const int bn = bnb * 128;
  const int bm = bmT * 128;

  // staging: waves 0,1 -> A, waves 2,3 -> B. 4 issues/wave/chunk (16B/lane).
  // granule index gi in [0,512): m = gi>>2, g' = gi&3; global col granule
  // g = g' ^ ((m>>1)&3)  (inverse-swizzled source, linear LDS dest).
  const unsigned short* gsrc[4];
  int ldoff[4];
  unsigned short* sb0;
  unsigned short* sb1;
  {
    const unsigned short* gb = (wave < 2) ? (A + (size_t)bm * K) : (Wt + (size_t)bn * K);
    sb0 = (wave < 2) ? ls0A : ls0B;
    sb1 = (wave < 2) ? ls1A : ls1B;
    int w01 = wave & 1;
#pragma unroll
    for (int t = 0; t < 4; t++) {
      int gi = (w01 * 4 + t) * 64 + lane;
      int m = gi >> 2;
      int gp = gi & 3;
      int gcol = (gp ^ ((m >> 1) & 3)) * 8;
      gsrc[t] = gb + (size_t)m * K + gcol;
      ldoff[t] = (w01 * 4 + t) * 512;       // ushort units; 1024B per issue
    }
  }

  const int wm = (wave & 1) * 64;
  const int wn = (wave >> 1) * 64;
  const int r15 = lane & 15;
  const int quad = lane >> 4;
  const int gpR = quad ^ ((r15 >> 1) & 3);   // read-side swizzled granule

  // early scatter-row prefetch (epilogue rows): overlaps the whole K-loop
  int orow[4][4];
#pragma unroll
  for (int i = 0; i < 4; i++)
#pragma unroll
    for (int r = 0; r < 4; r++) {
      int row = bm + wm + i * 16 + quad * 4 + r;
      orow[i][r] = idx ? idx[row * idxStride] : row;
    }

  f32x4 acc[4][4];
  f32x4 zero = {0.f, 0.f, 0.f, 0.f};
#pragma unroll
  for (int i = 0; i < 4; i++)
#pragma unroll
    for (int j = 0; j < 4; j++) acc[i][j] = zero;

  // prologue: stage chunk 0 into buffer 0
#pragma unroll
  for (int t = 0; t < 4; t++) { async16(gsrc[t], sb0 + ldoff[t]); gsrc[t] += 32; }

  const int nk = K >> 5;
  for (int c = 0; c < nk; c++) {
    __syncthreads();                       // publish chunk c (drains prefetch)
    if (c + 1 < nk) {                      // prefetch chunk c+1 into other buf
      unsigned short* d = ((c + 1) & 1) ? sb1 : sb0;
#pragma unroll
      for (int t = 0; t < 4; t++) { async16(gsrc[t], d + ldoff[t]); gsrc[t] += 32; }
    }
    const unsigned short* cA = (c & 1) ? ls1A : ls0A;
    const unsigned short* cB = (c & 1) ? ls1B : ls0B;
    short8 af[4], bf[4];
#pragma unroll
    for (int f = 0; f < 4; f++) {
      af[f] = *(const short8*)&cA[(wm + f * 16 + r15) * 32 + gpR * 8];
      bf[f] = *(const short8*)&cB[(wn + f * 16 + r15) * 32 + gpR * 8];
    }
#pragma unroll
    for (int i = 0; i < 4; i++)
#pragma unroll
      for (int j = 0; j < 4; j++)
        acc[i][j] = __builtin_amdgcn_mfma_f32_16x16x32_bf16(af[i], bf[j], acc[i][j], 0, 0, 0);
  }

  // D layout: row = quad*4+reg, col = lane&15 (m89/m91 verified)
#pragma unroll
  for (int i = 0; i < 4; i++) {
#pragma unroll
    for (int r = 0; r < 4; r++) {
      size_t rb = (size_t)orow[i][r] * N;
#pragma unroll
      for (int j = 0; j < 4; j++) {
        int col = bn + wn + j * 16 + r15;
        float v = acc[i][j][r];
        if (bias) v += b2f(bias[col]);
        if (actS) v += b2f(actS[rb + col]);
        out[rb + col] = f2b(v);
      }
    }
  }
}

// ---------------------------------------------------------------------------
// softmax + molecule segment-sum over a logits chunk L[65536, 512] (bf16).
// Chunk holds atoms [chunkBase, chunkBase+65536) = 16 atoms per molecule
// (stride 4096). One wave per molecule-slot; lane owns 8 contiguous cols.
// ---------------------------------------------------------------------------
__global__ __launch_bounds__(256) void k_smseg(
    const unsigned short* __restrict__ L, const int* __restrict__ mol,
    int chunkBase, int accum, float* __restrict__ fp)
{
  int slot = blockIdx.x * 4 + (threadIdx.x >> 6);   // 0..4095
  int lane = threadIdx.x & 63;
  float acc[8];
#pragma unroll
  for (int c = 0; c < 8; c++) acc[c] = 0.f;

  for (int k = 0; k < 16; k++) {
    int rloc = slot + (k << 12);
    short8 v = *(const short8*)&L[(size_t)rloc * 512 + lane * 8];
    float f[8];
    float m = -1e30f;
#pragma unroll
    for (int c = 0; c < 8; c++) { f[c] = b2f((unsigned short)v[c]); m = fmaxf(m, f[c]); }
#pragma unroll
    for (int s = 1; s <= 32; s <<= 1) m = fmaxf(m, __shfl_xor(m, s, 64));
    float sum = 0.f;
#pragma unroll
    for (int c = 0; c < 8; c++) { f[c] = __expf(f[c] - m); sum += f[c]; }
#pragma unroll
    for (int s = 1; s <= 32; s <<= 1) sum += __shfl_xor(sum, s, 64);
    float inv = 1.0f / sum;
#pragma unroll
    for (int c = 0; c < 8; c++) acc[c] += f[c] * inv;
  }

  int molid = mol[chunkBase + slot];
  float* dst = fp + (size_t)molid * 512 + lane * 8;
  if (accum) {
#pragma unroll
    for (int c = 0; c < 8; c++) dst[c] += acc[c];
  } else {
#pragma unroll
    for (int c = 0; c < 8; c++) dst[c] = acc[c];
  }
}

// ---------------------------------------------------------------------------
// gather: G[r] = [ sum_{j<=d} feat[anbr[r][j]], sum_{j<d} bond[bnbr[r][j]] ]
// feat canonical bf16; bond raw input (dual dtype via flag).
// ---------------------------------------------------------------------------
__global__ __launch_bounds__(256) void k_gather(
    const unsigned short* __restrict__ feat, const void* __restrict__ bond,
    const int* __restrict__ anbr, const int* __restrict__ bnbr,
    int d, int fin, unsigned short* __restrict__ G, const int* __restrict__ flag)
{
  int row = blockIdx.x * 4 + (threadIdx.x >> 6);
  int lane = threadIdx.x & 63;
  int W = fin + 64;
  int fl = *flag;
  const int* ar = anbr + (size_t)row * (d + 1);
  const int* br = bnbr + (size_t)row * d;
  for (int e2 = lane; e2 * 2 < W; e2 += 64) {
    int e = e2 * 2;
    float a0 = 0.f, a1 = 0.f;
    if (e < fin) {
      for (int j = 0; j <= d; j++) {
        unsigned p = *(const unsigned*)((const unsigned short*)feat + (size_t)ar[j] * fin + e);
        a0 += b2f((unsigned short)p);
        a1 += b2f((unsigned short)(p >> 16));
      }
    } else {
      int eb = e - fin;
      if (fl) {
        const float* bp = (const float*)bond;
        for (int j = 0; j < d; j++) {
          size_t o = (size_t)br[j] * 64 + eb;
          a0 += bp[o]; a1 += bp[o + 1];
        }
      } else {
        const unsigned short* bp = (const unsigned short*)bond;
        for (int j = 0; j < d; j++) {
          unsigned p = *(const unsigned*)(bp + (size_t)br[j] * 64 + eb);
          a0 += b2f((unsigned short)p);
          a1 += b2f((unsigned short)(p >> 16));
        }
      }
    }
    *(unsigned*)(G + (size_t)row * W + e) = (unsigned)f2b(a0) | ((unsigned)f2b(a1) << 16);
  }
}

// ---------------------------------------------------------------------------
// BatchNorm stats + normalize/ReLU in place (canonical bf16)
// ---------------------------------------------------------------------------
__global__ __launch_bounds__(256) void k_bnstats(const unsigned short* __restrict__ act,
                                                 float* __restrict__ st, int C) {
  int t = threadIdx.x;
  size_t r0 = (size_t)blockIdx.x * 256;
  int two = (C == 512);
  float s0 = 0, q0 = 0, s1 = 0, q1 = 0;
  for (int r = 0; r < 256; r++) {
    const unsigned short* rp = act + (r0 + r) * (size_t)C;
    float v = b2f(rp[t]); s0 += v; q0 += v * v;
    if (two) { float w = b2f(rp[t + 256]); s1 += w; q1 += w * w; }
  }
  atomicAdd(&st[t], s0);
  atomicAdd(&st[C + t], q0);
  if (two) { atomicAdd(&st[t + 256], s1); atomicAdd(&st[C + t + 256], q1); }
}
__global__ __launch_bounds__(256) void k_bnrelu(unsigned short* __restrict__ act,
                                                const float* __restrict__ st, int C, float invN) {
  size_t i = (size_t)blockIdx.x * 256 + threadIdx.x;
  unsigned p = ((unsigned*)act)[i];
  int c0 = (int)((2 * i) & (size_t)(C - 1));
  float mu0 = st[c0] * invN, mu1 = st[c0 + 1] * invN;
  float sc0 = rsqrtf(st[C + c0] * invN - mu0 * mu0 + 1e-5f);
  float sc1 = rsqrtf(st[C + c0 + 1] * invN - mu1 * mu1 + 1e-5f);
  float v0 = fmaxf((b2f((unsigned short)p) - mu0) * sc0, 0.f);
  float v1 = fmaxf((b2f((unsigned short)(p >> 16)) - mu1) * sc1, 0.f);
  ((unsigned*)act)[i] = (unsigned)f2b(v0) | ((unsigned)f2b(v1) << 16);
}

__global__ void k_out(const float* __restrict__ fp, void* __restrict__ out,
                      const int* __restrict__ flag) {
  size_t i = (size_t)blockIdx.x * 256 + threadIdx.x;   // pair index
  float a = fp[2 * i], b = fp[2 * i + 1];
  if (*flag) {
    ((float*)out)[2 * i] = a;
    ((float*)out)[2 * i + 1] = b;
  } else {
    ((unsigned*)out)[i] = (unsigned)f2b(a) | ((unsigned)f2b(b) << 16);
  }
}

// ---------------------------------------------------------------------------
extern "C" void kernel_launch(void* const* d_in, const int* in_sizes, int n_in,
                              void* d_out, int out_size, void* d_ws, size_t ws_size,
                              hipStream_t stream)
{
  const void* atomRaw = d_in[0];
  const void* bondRaw = d_in[1];
  const int* mol = (const int*)d_in[2];

  const int* anbr[4]; const int* bnbr[4];
  if (in_sizes[4] == NDEG) {       // dict order: anbr_d1, bnbr_d1, anbr_d2, ...
    for (int g = 0; g < 4; g++) { anbr[g] = (const int*)d_in[3 + 2 * g]; bnbr[g] = (const int*)d_in[4 + 2 * g]; }
  } else {                         // signature order
    for (int g = 0; g < 4; g++) { anbr[g] = (const int*)d_in[3 + g]; bnbr[g] = (const int*)d_in[7 + g]; }
  }
  const void* W_self[2] = {d_in[11], d_in[17]};
  const void* biasL[2]  = {d_in[12], d_in[18]};
  const void* W_deg[2][4];
  for (int g = 0; g < 4; g++) { W_deg[0][g] = d_in[13 + g]; W_deg[1][g] = d_in[19 + g]; }
  const void* W_out[3] = {d_in[23], d_in[25], d_in[27]};
  const void* b_out[3] = {d_in[24], d_in[26], d_in[28]};

  // ---- workspace carve (~224 MiB; atomC aliases Y) ----
  char* p = (char*)d_ws;
  auto alloc = [&](size_t bytes) { void* r = p; p += (bytes + 255) & ~(size_t)255; return r; };
  unsigned short* X  = (unsigned short*)alloc((size_t)NATOMS * 256 * 2);   // 64 MiB
  unsigned short* G  = (unsigned short*)alloc((size_t)NDEG * 320 * 2);     // 20 MiB
  float* fp          = (float*)alloc((size_t)NMOL * 512 * 4);              // 8 MiB
  unsigned short* wtSelf0 = (unsigned short*)alloc(128 * 256 * 2);
  unsigned short* wtSelf1 = (unsigned short*)alloc(256 * 512 * 2);
  unsigned short* wtDeg0[4], *wtDeg1[4];
  for (int g = 0; g < 4; g++) wtDeg0[g] = (unsigned short*)alloc(192 * 256 * 2);
  for (int g = 0; g < 4; g++) wtDeg1[g] = (unsigned short*)alloc(320 * 512 * 2);
  unsigned short* wtOut0 = (unsigned short*)alloc(128 * 512 * 2);
  unsigned short* wtOut1 = (unsigned short*)alloc(256 * 512 * 2);
  unsigned short* wtOut2 = (unsigned short*)alloc(512 * 512 * 2);
  unsigned short* biasC0 = (unsigned short*)alloc(256 * 2);
  unsigned short* biasC1 = (unsigned short*)alloc(512 * 2);
  unsigned short* bOutC[3];
  for (int g = 0; g < 3; g++) bOutC[g] = (unsigned short*)alloc(512 * 2);
  float* st = (float*)alloc(2 * 512 * 4);
  int* flag = (int*)alloc(256);
  unsigned short* Y = (unsigned short*)alloc((size_t)NATOMS * 512 * 2);    // 128 MiB
  unsigned short* atomC = Y;   // alias: atomC (32 MiB) dead before first Y write

  size_t need = (size_t)(p - (char*)d_ws);
  if (ws_size < need) {                        // clean fail instead of OOB fault
    hipMemsetAsync(d_out, 0, (size_t)out_size * 2, stream);
    return;
  }

  const float invN = 1.0f / (float)NATOMS;
  const int MH = NATOMS / 2;                   // 65536-atom logits chunks

  hipMemsetAsync(flag, 0, 4, stream);
  k_flag<<<dim3(1), dim3(256), 0, stream>>>((const unsigned short*)atomRaw, flag);

  // canonical bf16 atom copy (into Y-alias)
  k_cvt<<<dim3(NATOMS * 64 / 256), dim3(256), 0, stream>>>(atomRaw, atomC, NATOMS * 64, flag);

  // one launch: 13 transposes + 5 bias copies
  {
    PrepArgs pa;
    int n = 0;
    auto T = [&](const void* s, unsigned short* d, int K, int N) { pa.d[n++] = {s, d, K, N}; };
    auto C = [&](const void* s, unsigned short* d, int N)        { pa.d[n++] = {s, d, 0, N}; };
    T(W_self[0], wtSelf0, 128, 256);
    T(W_self[1], wtSelf1, 256, 512);
    for (int g = 0; g < 4; g++) T(W_deg[0][g], wtDeg0[g], 192, 256);
    for (int g = 0; g < 4; g++) T(W_deg[1][g], wtDeg1[g], 320, 512);
    T(W_out[0], wtOut0, 128, 512);
    T(W_out[1], wtOut1, 256, 512);
    T(W_out[2], wtOut2, 512, 512);
    C(biasL[0], biasC0, 256);
    C(biasL[1], biasC1, 512);
    for (int g = 0; g < 3; g++) C(b_out[g], bOutC[g], 512);
    k_prep<<<dim3(1024, 18), dim3(256), 0, stream>>>(pa, flag);
  }

  auto GEMM = [&](const unsigned short* A, const unsigned short* Wt, int M, int N, int K,
                  const unsigned short* bias, const unsigned short* actS,
                  const int* idx, int idxStride, unsigned short* out) {
    int nblocks = (M / 128) * (N / 128);
    k_gemm<<<dim3(nblocks), dim3(256), 0, stream>>>(A, Wt, M, N, K, bias, actS,
                                                    idx, idxStride, out);
  };

  // fingerprint round: logits via k_gemm into scratch (bf16, M=65536 chunks),
  // then k_smseg. round r uses scratch buffer dead at that point.
  auto FPROUND = [&](const unsigned short* A, const unsigned short* WtO, int K,
                     const unsigned short* bias, unsigned short* scratch, int firstRound) {
    for (int c = 0; c < 2; c++) {
      GEMM(A + (size_t)c * MH * K, WtO, MH, 512, K, bias, nullptr, nullptr, 0, scratch);
      k_smseg<<<dim3(NMOL / 4), dim3(256), 0, stream>>>(scratch, mol, c * MH,
                                                        (firstRound && c == 0) ? 0 : 1, fp);
    }
  };

  // ---- fp round 0 (atomC in Y-alias, K=128; scratch = X, not yet live) ----
  FPROUND(atomC, wtOut0, 128, bOutC[0], X, 1);

  // ---- conv layer 0 (128 -> 256), in-place nbr add on X ----
  GEMM(atomC, wtSelf0, NATOMS, 256, 128, biasC0, nullptr, nullptr, 0, X);
  for (int g = 0; g < 4; g++) {
    int d = g + 1;
    k_gather<<<dim3(NDEG / 4), dim3(256), 0, stream>>>(atomC, bondRaw, anbr[g], bnbr[g], d, 128, G, flag);
    GEMM(G, wtDeg0[g], NDEG, 256, 192, nullptr, X, anbr[g], d + 1, X);
  }
  hipMemsetAsync(st, 0, 2 * 512 * 4, stream);
  k_bnstats<<<dim3(NATOMS / 256), dim3(256), 0, stream>>>(X, st, 256);
  k_bnrelu<<<dim3(NATOMS * 256 / 2 / 256), dim3(256), 0, stream>>>(X, st, 256, invN);

  // ---- fp round 1 (X, K=256; scratch = Y, atomC dead, Y not yet live) ----
  FPROUND(X, wtOut1, 256, bOutC[1], Y, 0);

  // ---- conv layer 1 (256 -> 512), in-place nbr add on Y ----
  GEMM(X, wtSelf1, NATOMS, 512, 256, biasC1, nullptr, nullptr, 0, Y);
  for (int g = 0; g < 4; g++) {
    int d = g + 1;
    k_gather<<<dim3(NDEG / 4), dim3(256), 0, stream>>>(X, bondRaw, anbr[g], bnbr[g], d, 256, G, flag);
    GEMM(G, wtDeg1[g], NDEG, 512, 320, nullptr, Y, anbr[g], d + 1, Y);
  }
  hipMemsetAsync(st, 0, 2 * 512 * 4, stream);
  k_bnstats<<<dim3(NATOMS / 256), dim3(256), 0, stream>>>(Y, st, 512);
  k_bnrelu<<<dim3(NATOMS * 512 / 2 / 256), dim3(256), 0, stream>>>(Y, st, 512, invN);

  // ---- fp round 2 (Y, K=512; scratch = X, dead after conv layer 1) ----
  FPROUND(Y, wtOut2, 512, bOutC[2], X, 0);

  k_out<<<dim3(NMOL * 256 / 256), dim3(256), 0, stream>>>(fp, d_out, flag);
}

// Round 3
// 1495.343 us; speedup vs baseline: 1.5187x; 1.0692x over previous
//
#include <hip/hip_runtime.h>
#include <stdint.h>

// ---------------------------------------------------------------------------
// NeuralFingerprint on MI355X (gfx950). Inputs float32 (runtime-probed),
// canonicalized to bf16. R9: R8 profile shows k_bnstats is the #1 dispatch
// (121us for a 64MiB pass = 7% HBM, scalar 2B loads, latency-bound). Changes:
//   (1) k_bnstats: short8 (16B/lane) grid-stride loads, per-thread 8-col f32
//       accumulators, LDS tree reduce, few global atomics. ~12x less latency
//       exposure.
//   (2) k_bnfin folds stats -> per-column (scale, shift); k_bnrelu widened to
//       short8 with vector table loads.
// GEMM path (BK=32, 5 blocks/CU, co-XCD remap, turnover grid) kept from R8.
// ---------------------------------------------------------------------------

typedef __attribute__((ext_vector_type(8))) short short8;
typedef __attribute__((ext_vector_type(4))) float f32x4;

#define NATOMS 131072
#define NDEG   32768
#define NMOL   4096

__device__ __forceinline__ float b2f(unsigned short u) {
  return __uint_as_float(((unsigned)u) << 16);
}
__device__ __forceinline__ unsigned short f2b(float f) {
  unsigned u = __float_as_uint(f);
  return (unsigned short)((u + 0x7fffu + ((u >> 16) & 1u)) >> 16);
}
__device__ __forceinline__ void async16(const void* g, void* l) {
  __builtin_amdgcn_global_load_lds(
      (const __attribute__((address_space(1))) void*)g,
      (__attribute__((address_space(3))) void*)l, 16, 0, 0);
}

// ---------------------------------------------------------------------------
// dtype probe: f32 buffers read-as-bf16 show garbage-exponent odd ushorts.
// ---------------------------------------------------------------------------
__global__ void k_flag(const unsigned short* __restrict__ a, int* __restrict__ flag) {
  int t = threadIdx.x;
  float x = b2f(a[t]), y = b2f(a[t + 256]);
  int bad = (fabsf(x) > 1e6f) || (fabsf(y) > 1e6f) || (x != x) || (y != y);
  if (bad) atomicOr(flag, 1);
}

// convert n2 bf16-pairs: src f32 (flag=1) or bf16 (flag=0)
__global__ void k_cvt(const void* __restrict__ src, unsigned short* __restrict__ dst,
                      int n2, const int* __restrict__ flag) {
  int i = blockIdx.x * 256 + threadIdx.x;
  if (i >= n2) return;
  if (*flag) {
    const float* s = (const float*)src;
    ((unsigned*)dst)[i] = (unsigned)f2b(s[2 * i]) | ((unsigned)f2b(s[2 * i + 1]) << 16);
  } else {
    ((unsigned*)dst)[i] = ((const unsigned*)src)[i];
  }
}

// ---------------------------------------------------------------------------
// one-shot prep: 13 weight transposes + 5 bias copies, f32/bf16 dual dtype.
// ---------------------------------------------------------------------------
struct PrepDesc { const void* src; unsigned short* dst; int K; int N; };
struct PrepArgs { PrepDesc d[18]; };

__global__ void k_prep(PrepArgs a, const int* __restrict__ flag) {
  const PrepDesc de = a.d[blockIdx.y];
  int elems = de.K ? de.K * de.N : de.N;
  int idx = blockIdx.x * 256 + threadIdx.x;
  if (idx >= elems) return;
  unsigned short v = (*flag) ? f2b(((const float*)de.src)[idx])
                             : ((const unsigned short*)de.src)[idx];
  if (de.K) {
    int k = idx / de.N, n = idx - k * de.N;
    de.dst[(size_t)n * de.K + k] = v;       // [K,N] -> [N,K]
  } else {
    de.dst[idx] = v;
  }
}

// ---------------------------------------------------------------------------
// GEMM: out[orow,N] = A[M,K] * Wt[N,K]^T (+bias[col]) (+actS[orow,col])
// orow = idx ? idx[row*idxStride] : row. In-place safe (actS == out).
// Tile 128x128, BK=32, LDS 32KB/block (5 blocks/CU). 1D grid with co-XCD
// remap: the nbn blocks sharing an A tile-row sit at IDs == same (mod 8).
// LDS layout per chunk: granule (m, g') holds global granule g = g'^((m>>1)&3)
// -> ds_read_b128 of a column-slice is bank-conflict-free (8 consecutive
// lanes cover all 8 bank groups).
// ---------------------------------------------------------------------------
__global__ __launch_bounds__(256) void k_gemm(
    const unsigned short* __restrict__ A, const unsigned short* __restrict__ Wt,
    int M, int N, int K,
    const unsigned short* __restrict__ bias,
    const unsigned short* __restrict__ actS,
    const int* __restrict__ idx, int idxStride,
    unsigned short* __restrict__ out)
{
  __shared__ __attribute__((aligned(16))) unsigned short ls0A[128 * 32];
  __shared__ __attribute__((aligned(16))) unsigned short ls0B[128 * 32];
  __shared__ __attribute__((aligned(16))) unsigned short ls1A[128 * 32];
  __shared__ __attribute__((aligned(16))) unsigned short ls1B[128 * 32];

  const int tid  = threadIdx.x;
  const int wave = tid >> 6;
  const int lane = tid & 63;

  // --- co-XCD block remap: A-tile sharers congruent mod 8 ---
  const int nbn = N >> 7;
  int bmT, bnb;
  {
    int lin = blockIdx.x;
    int nT = gridDim.x / nbn;
    if ((nT & 7) == 0) {
      int r = lin & 7, rest = lin >> 3;
      bnb = rest % nbn;
      bmT = (rest / nbn) * 8 + r;
    } else {
      bnb = lin % nbn;
      bmT = lin / nbn;
    }
  }
  const int bn = bnb * 128;
  const int bm = bmT * 128;

  // staging: waves 0,1 -> A, waves 2,3 -> B. 4 issues/wave/chunk (16B/lane).
  // granule index gi in [0,512): m = gi>>2, g' = gi&3; global col granule
  // g = g' ^ ((m>>1)&3)  (inverse-swizzled source, linear LDS dest).
  const unsigned short* gsrc[4];
  int ldoff[4];
  unsigned short* sb0;
  unsigned short* sb1;
  {
    const unsigned short* gb = (wave < 2) ? (A + (size_t)bm * K) : (Wt + (size_t)bn * K);
    sb0 = (wave < 2) ? ls0A : ls0B;
    sb1 = (wave < 2) ? ls1A : ls1B;
    int w01 = wave & 1;
#pragma unroll
    for (int t = 0; t < 4; t++) {
      int gi = (w01 * 4 + t) * 64 + lane;
      int m = gi >> 2;
      int gp = gi & 3;
      int gcol = (gp ^ ((m >> 1) & 3)) * 8;
      gsrc[t] = gb + (size_t)m * K + gcol;
      ldoff[t] = (w01 * 4 + t) * 512;       // ushort units; 1024B per issue
    }
  }

  const int wm = (wave & 1) * 64;
  const int wn = (wave >> 1) * 64;
  const int r15 = lane & 15;
  const int quad = lane >> 4;
  const int gpR = quad ^ ((r15 >> 1) & 3);   // read-side swizzled granule

  // early scatter-row prefetch (epilogue rows): overlaps the whole K-loop
  int orow[4][4];
#pragma unroll
  for (int i = 0; i < 4; i++)
#pragma unroll
    for (int r = 0; r < 4; r++) {
      int row = bm + wm + i * 16 + quad * 4 + r;
      orow[i][r] = idx ? idx[row * idxStride] : row;
    }

  f32x4 acc[4][4];
  f32x4 zero = {0.f, 0.f, 0.f, 0.f};
#pragma unroll
  for (int i = 0; i < 4; i++)
#pragma unroll
    for (int j = 0; j < 4; j++) acc[i][j] = zero;

  // prologue: stage chunk 0 into buffer 0
#pragma unroll
  for (int t = 0; t < 4; t++) { async16(gsrc[t], sb0 + ldoff[t]); gsrc[t] += 32; }

  const int nk = K >> 5;
  for (int c = 0; c < nk; c++) {
    __syncthreads();                       // publish chunk c (drains prefetch)
    if (c + 1 < nk) {                      // prefetch chunk c+1 into other buf
      unsigned short* d = ((c + 1) & 1) ? sb1 : sb0;
#pragma unroll
      for (int t = 0; t < 4; t++) { async16(gsrc[t], d + ldoff[t]); gsrc[t] += 32; }
    }
    const unsigned short* cA = (c & 1) ? ls1A : ls0A;
    const unsigned short* cB = (c & 1) ? ls1B : ls0B;
    short8 af[4], bf[4];
#pragma unroll
    for (int f = 0; f < 4; f++) {
      af[f] = *(const short8*)&cA[(wm + f * 16 + r15) * 32 + gpR * 8];
      bf[f] = *(const short8*)&cB[(wn + f * 16 + r15) * 32 + gpR * 8];
    }
#pragma unroll
    for (int i = 0; i < 4; i++)
#pragma unroll
      for (int j = 0; j < 4; j++)
        acc[i][j] = __builtin_amdgcn_mfma_f32_16x16x32_bf16(af[i], bf[j], acc[i][j], 0, 0, 0);
  }

  // D layout: row = quad*4+reg, col = lane&15 (m89/m91 verified)
#pragma unroll
  for (int i = 0; i < 4; i++) {
#pragma unroll
    for (int r = 0; r < 4; r++) {
      size_t rb = (size_t)orow[i][r] * N;
#pragma unroll
      for (int j = 0; j < 4; j++) {
        int col = bn + wn + j * 16 + r15;
        float v = acc[i][j][r];
        if (bias) v += b2f(bias[col]);
        if (actS) v += b2f(actS[rb + col]);
        out[rb + col] = f2b(v);
      }
    }
  }
}

// ---------------------------------------------------------------------------
// softmax + molecule segment-sum over a logits chunk L[65536, 512] (bf16).
// Chunk holds atoms [chunkBase, chunkBase+65536) = 16 atoms per molecule
// (stride 4096). One wave per molecule-slot; lane owns 8 contiguous cols.
// ---------------------------------------------------------------------------
__global__ __launch_bounds__(256) void k_smseg(
    const unsigned short* __restrict__ L, const int* __restrict__ mol,
    int chunkBase, int accum, float* __restrict__ fp)
{
  int slot = blockIdx.x * 4 + (threadIdx.x >> 6);   // 0..4095
  int lane = threadIdx.x & 63;
  float acc[8];
#pragma unroll
  for (int c = 0; c < 8; c++) acc[c] = 0.f;

  for (int k = 0; k < 16; k++) {
    int rloc = slot + (k << 12);
    short8 v = *(const short8*)&L[(size_t)rloc * 512 + lane * 8];
    float f[8];
    float m = -1e30f;
#pragma unroll
    for (int c = 0; c < 8; c++) { f[c] = b2f((unsigned short)v[c]); m = fmaxf(m, f[c]); }
#pragma unroll
    for (int s = 1; s <= 32; s <<= 1) m = fmaxf(m, __shfl_xor(m, s, 64));
    float sum = 0.f;
#pragma unroll
    for (int c = 0; c < 8; c++) { f[c] = __expf(f[c] - m); sum += f[c]; }
#pragma unroll
    for (int s = 1; s <= 32; s <<= 1) sum += __shfl_xor(sum, s, 64);
    float inv = 1.0f / sum;
#pragma unroll
    for (int c = 0; c < 8; c++) acc[c] += f[c] * inv;
  }

  int molid = mol[chunkBase + slot];
  float* dst = fp + (size_t)molid * 512 + lane * 8;
  if (accum) {
#pragma unroll
    for (int c = 0; c < 8; c++) dst[c] += acc[c];
  } else {
#pragma unroll
    for (int c = 0; c < 8; c++) dst[c] = acc[c];
  }
}

// ---------------------------------------------------------------------------
// gather: G[r] = [ sum_{j<=d} feat[anbr[r][j]], sum_{j<d} bond[bnbr[r][j]] ]
// feat canonical bf16; bond raw input (dual dtype via flag).
// ---------------------------------------------------------------------------
__global__ __launch_bounds__(256) void k_gather(
    const unsigned short* __restrict__ feat, const void* __restrict__ bond,
    const int* __restrict__ anbr, const int* __restrict__ bnbr,
    int d, int fin, unsigned short* __restrict__ G, const int* __restrict__ flag)
{
  int row = blockIdx.x * 4 + (threadIdx.x >> 6);
  int lane = threadIdx.x & 63;
  int W = fin + 64;
  int fl = *flag;
  const int* ar = anbr + (size_t)row * (d + 1);
  const int* br = bnbr + (size_t)row * d;
  for (int e2 = lane; e2 * 2 < W; e2 += 64) {
    int e = e2 * 2;
    float a0 = 0.f, a1 = 0.f;
    if (e < fin) {
      for (int j = 0; j <= d; j++) {
        unsigned p = *(const unsigned*)((const unsigned short*)feat + (size_t)ar[j] * fin + e);
        a0 += b2f((unsigned short)p);
        a1 += b2f((unsigned short)(p >> 16));
      }
    } else {
      int eb = e - fin;
      if (fl) {
        const float* bp = (const float*)bond;
        for (int j = 0; j < d; j++) {
          size_t o = (size_t)br[j] * 64 + eb;
          a0 += bp[o]; a1 += bp[o + 1];
        }
      } else {
        const unsigned short* bp = (const unsigned short*)bond;
        for (int j = 0; j < d; j++) {
          unsigned p = *(const unsigned*)(bp + (size_t)br[j] * 64 + eb);
          a0 += b2f((unsigned short)p);
          a1 += b2f((unsigned short)(p >> 16));
        }
      }
    }
    *(unsigned*)(G + (size_t)row * W + e) = (unsigned)f2b(a0) | ((unsigned)f2b(a1) << 16);
  }
}

// ---------------------------------------------------------------------------
// BatchNorm stats: short8 grid-stride loads, 8-col f32 accumulators per
// thread, LDS tree reduce, <=2C global atomics per block.
// tpr = C/8 threads cover one row; stride rows = gridDim*256/tpr.
// ---------------------------------------------------------------------------
__global__ __launch_bounds__(256) void k_bnstats(const unsigned short* __restrict__ act,
                                                 float* __restrict__ st, int C) {
  __shared__ float red[2][256][8];
  const int tpr = C >> 3;                       // 32 (C=256) or 64 (C=512)
  const int tid = threadIdx.x;
  const int gtid = blockIdx.x * 256 + tid;
  const int colg = tid & (tpr - 1);             // 256 % tpr == 0
  const int rowStart = gtid / tpr;
  const int stride = (gridDim.x * 256) / tpr;

  float s[8], q[8];
#pragma unroll
  for (int c = 0; c < 8; c++) { s[c] = 0.f; q[c] = 0.f; }

#pragma unroll 4
  for (int r = rowStart; r < NATOMS; r += stride) {
    short8 v = *(const short8*)&act[(size_t)r * C + colg * 8];
#pragma unroll
    for (int c = 0; c < 8; c++) {
      float f = b2f((unsigned short)v[c]);
      s[c] += f; q[c] += f * f;
    }
  }
#pragma unroll
  for (int c = 0; c < 8; c++) { red[0][tid][c] = s[c]; red[1][tid][c] = q[c]; }
  __syncthreads();
  for (int j = tid; j < C; j += 256) {
    int g = j >> 3, c = j & 7;
    float ss = 0.f, qq = 0.f;
    for (int k = g; k < 256; k += tpr) { ss += red[0][k][c]; qq += red[1][k][c]; }
    atomicAdd(&st[j], ss);
    atomicAdd(&st[C + j], qq);
  }
}

// fold stats -> per-column scale/shift pairs: fin[2c] = sc, fin[2c+1] = -mu*sc
__global__ void k_bnfin(const float* __restrict__ st, float* __restrict__ fin,
                        int C, float invN) {
  int c = blockIdx.x * 256 + threadIdx.x;
  if (c >= C) return;
  float mu = st[c] * invN;
  float sc = rsqrtf(st[C + c] * invN - mu * mu + 1e-5f);
  fin[2 * c] = sc;
  fin[2 * c + 1] = -mu * sc;
}

// normalize + ReLU, short8 (16B/lane), vector table loads
__global__ __launch_bounds__(256) void k_bnrelu(unsigned short* __restrict__ act,
                                                const float* __restrict__ fin, int C) {
  size_t i = ((size_t)blockIdx.x * 256 + threadIdx.x) * 8;   // element index
  short8 v = *(short8*)&act[i];
  int c0 = (int)(i & (size_t)(C - 1));
  f32x4 t0 = *(const f32x4*)&fin[2 * c0];
  f32x4 t1 = *(const f32x4*)&fin[2 * c0 + 4];
  f32x4 t2 = *(const f32x4*)&fin[2 * c0 + 8];
  f32x4 t3 = *(const f32x4*)&fin[2 * c0 + 12];
  float sc[8] = {t0[0], t0[2], t1[0], t1[2], t2[0], t2[2], t3[0], t3[2]};
  float sh[8] = {t0[1], t0[3], t1[1], t1[3], t2[1], t2[3], t3[1], t3[3]};
  short8 o;
#pragma unroll
  for (int c = 0; c < 8; c++) {
    float f = fmaxf(b2f((unsigned short)v[c]) * sc[c] + sh[c], 0.f);
    o[c] = (short)f2b(f);
  }
  *(short8*)&act[i] = o;
}

__global__ void k_out(const float* __restrict__ fp, void* __restrict__ out,
                      const int* __restrict__ flag) {
  size_t i = (size_t)blockIdx.x * 256 + threadIdx.x;   // pair index
  float a = fp[2 * i], b = fp[2 * i + 1];
  if (*flag) {
    ((float*)out)[2 * i] = a;
    ((float*)out)[2 * i + 1] = b;
  } else {
    ((unsigned*)out)[i] = (unsigned)f2b(a) | ((unsigned)f2b(b) << 16);
  }
}

// ---------------------------------------------------------------------------
extern "C" void kernel_launch(void* const* d_in, const int* in_sizes, int n_in,
                              void* d_out, int out_size, void* d_ws, size_t ws_size,
                              hipStream_t stream)
{
  const void* atomRaw = d_in[0];
  const void* bondRaw = d_in[1];
  const int* mol = (const int*)d_in[2];

  const int* anbr[4]; const int* bnbr[4];
  if (in_sizes[4] == NDEG) {       // dict order: anbr_d1, bnbr_d1, anbr_d2, ...
    for (int g = 0; g < 4; g++) { anbr[g] = (const int*)d_in[3 + 2 * g]; bnbr[g] = (const int*)d_in[4 + 2 * g]; }
  } else {                         // signature order
    for (int g = 0; g < 4; g++) { anbr[g] = (const int*)d_in[3 + g]; bnbr[g] = (const int*)d_in[7 + g]; }
  }
  const void* W_self[2] = {d_in[11], d_in[17]};
  const void* biasL[2]  = {d_in[12], d_in[18]};
  const void* W_deg[2][4];
  for (int g = 0; g < 4; g++) { W_deg[0][g] = d_in[13 + g]; W_deg[1][g] = d_in[19 + g]; }
  const void* W_out[3] = {d_in[23], d_in[25], d_in[27]};
  const void* b_out[3] = {d_in[24], d_in[26], d_in[28]};

  // ---- workspace carve (~224 MiB; atomC aliases Y) ----
  char* p = (char*)d_ws;
  auto alloc = [&](size_t bytes) { void* r = p; p += (bytes + 255) & ~(size_t)255; return r; };
  unsigned short* X  = (unsigned short*)alloc((size_t)NATOMS * 256 * 2);   // 64 MiB
  unsigned short* G  = (unsigned short*)alloc((size_t)NDEG * 320 * 2);     // 20 MiB
  float* fp          = (float*)alloc((size_t)NMOL * 512 * 4);              // 8 MiB
  unsigned short* wtSelf0 = (unsigned short*)alloc(128 * 256 * 2);
  unsigned short* wtSelf1 = (unsigned short*)alloc(256 * 512 * 2);
  unsigned short* wtDeg0[4], *wtDeg1[4];
  for (int g = 0; g < 4; g++) wtDeg0[g] = (unsigned short*)alloc(192 * 256 * 2);
  for (int g = 0; g < 4; g++) wtDeg1[g] = (unsigned short*)alloc(320 * 512 * 2);
  unsigned short* wtOut0 = (unsigned short*)alloc(128 * 512 * 2);
  unsigned short* wtOut1 = (unsigned short*)alloc(256 * 512 * 2);
  unsigned short* wtOut2 = (unsigned short*)alloc(512 * 512 * 2);
  unsigned short* biasC0 = (unsigned short*)alloc(256 * 2);
  unsigned short* biasC1 = (unsigned short*)alloc(512 * 2);
  unsigned short* bOutC[3];
  for (int g = 0; g < 3; g++) bOutC[g] = (unsigned short*)alloc(512 * 2);
  float* st = (float*)alloc(2 * 512 * 4);
  float* fin = (float*)alloc(2 * 512 * 4);
  int* flag = (int*)alloc(256);
  unsigned short* Y = (unsigned short*)alloc((size_t)NATOMS * 512 * 2);    // 128 MiB
  unsigned short* atomC = Y;   // alias: atomC (32 MiB) dead before first Y write

  size_t need = (size_t)(p - (char*)d_ws);
  if (ws_size < need) {                        // clean fail instead of OOB fault
    hipMemsetAsync(d_out, 0, (size_t)out_size * 2, stream);
    return;
  }

  const float invN = 1.0f / (float)NATOMS;
  const int MH = NATOMS / 2;                   // 65536-atom logits chunks

  hipMemsetAsync(flag, 0, 4, stream);
  k_flag<<<dim3(1), dim3(256), 0, stream>>>((const unsigned short*)atomRaw, flag);

  // canonical bf16 atom copy (into Y-alias)
  k_cvt<<<dim3(NATOMS * 64 / 256), dim3(256), 0, stream>>>(atomRaw, atomC, NATOMS * 64, flag);

  // one launch: 13 transposes + 5 bias copies
  {
    PrepArgs pa;
    int n = 0;
    auto T = [&](const void* s, unsigned short* d, int K, int N) { pa.d[n++] = {s, d, K, N}; };
    auto C = [&](const void* s, unsigned short* d, int N)        { pa.d[n++] = {s, d, 0, N}; };
    T(W_self[0], wtSelf0, 128, 256);
    T(W_self[1], wtSelf1, 256, 512);
    for (int g = 0; g < 4; g++) T(W_deg[0][g], wtDeg0[g], 192, 256);
    for (int g = 0; g < 4; g++) T(W_deg[1][g], wtDeg1[g], 320, 512);
    T(W_out[0], wtOut0, 128, 512);
    T(W_out[1], wtOut1, 256, 512);
    T(W_out[2], wtOut2, 512, 512);
    C(biasL[0], biasC0, 256);
    C(biasL[1], biasC1, 512);
    for (int g = 0; g < 3; g++) C(b_out[g], bOutC[g], 512);
    k_prep<<<dim3(1024, 18), dim3(256), 0, stream>>>(pa, flag);
  }

  auto GEMM = [&](const unsigned short* A, const unsigned short* Wt, int M, int N, int K,
                  const unsigned short* bias, const unsigned short* actS,
                  const int* idx, int idxStride, unsigned short* out) {
    int nblocks = (M / 128) * (N / 128);
    k_gemm<<<dim3(nblocks), dim3(256), 0, stream>>>(A, Wt, M, N, K, bias, actS,
                                                    idx, idxStride, out);
  };

  // BN: stats (vectorized) -> fold -> normalize+ReLU (vectorized)
  auto BN = [&](unsigned short* act, int C) {
    hipMemsetAsync(st, 0, 2 * 512 * 4, stream);
    k_bnstats<<<dim3(1024), dim3(256), 0, stream>>>(act, st, C);
    k_bnfin<<<dim3((C + 255) / 256), dim3(256), 0, stream>>>(st, fin, C, invN);
    k_bnrelu<<<dim3(NATOMS * C / 8 / 256), dim3(256), 0, stream>>>(act, fin, C);
  };

  // fingerprint round: logits via k_gemm into scratch (bf16, M=65536 chunks),
  // then k_smseg. round r uses scratch buffer dead at that point.
  auto FPROUND = [&](const unsigned short* A, const unsigned short* WtO, int K,
                     const unsigned short* bias, unsigned short* scratch, int firstRound) {
    for (int c = 0; c < 2; c++) {
      GEMM(A + (size_t)c * MH * K, WtO, MH, 512, K, bias, nullptr, nullptr, 0, scratch);
      k_smseg<<<dim3(NMOL / 4), dim3(256), 0, stream>>>(scratch, mol, c * MH,
                                                        (firstRound && c == 0) ? 0 : 1, fp);
    }
  };

  // ---- fp round 0 (atomC in Y-alias, K=128; scratch = X, not yet live) ----
  FPROUND(atomC, wtOut0, 128, bOutC[0], X, 1);

  // ---- conv layer 0 (128 -> 256), in-place nbr add on X ----
  GEMM(atomC, wtSelf0, NATOMS, 256, 128, biasC0, nullptr, nullptr, 0, X);
  for (int g = 0; g < 4; g++) {
    int d = g + 1;
    k_gather<<<dim3(NDEG / 4), dim3(256), 0, stream>>>(atomC, bondRaw, anbr[g], bnbr[g], d, 128, G, flag);
    GEMM(G, wtDeg0[g], NDEG, 256, 192, nullptr, X, anbr[g], d + 1, X);
  }
  BN(X, 256);

  // ---- fp round 1 (X, K=256; scratch = Y, atomC dead, Y not yet live) ----
  FPROUND(X, wtOut1, 256, bOutC[1], Y, 0);

  // ---- conv layer 1 (256 -> 512), in-place nbr add on Y ----
  GEMM(X, wtSelf1, NATOMS, 512, 256, biasC1, nullptr, nullptr, 0, Y);
  for (int g = 0; g < 4; g++) {
    int d = g + 1;
    k_gather<<<dim3(NDEG / 4), dim3(256), 0, stream>>>(X, bondRaw, anbr[g], bnbr[g], d, 256, G, flag);
    GEMM(G, wtDeg1[g], NDEG, 512, 320, nullptr, Y, anbr[g], d + 1, Y);
  }
  BN(Y, 512);

  // ---- fp round 2 (Y, K=512; scratch = X, dead after conv layer 1) ----
  FPROUND(Y, wtOut2, 512, bOutC[2], X, 0);

  k_out<<<dim3(NMOL * 256 / 256), dim3(256), 0, stream>>>(fp, d_out, flag);
}